// Round 15
// baseline (223.425 us; speedup 1.0000x reference)
//
#include <hip/hip_runtime.h>

// NRI MLP decoder, single step. B=8, N=32, T=256, D=4, E=992, K=2, H=64, M=64, NH=128.
// Edge e: receiver i=e/31, jj=e%31, sender j = jj<i ? jj : jj+1.
// h1 = relu(S[j]+R[i]), S = x@W1[k][0:4]+b1 (senders first), R = x@W1[k][4:8].
// msg = relu(h1@W2[k]+b2[k]); agg[i] += msg*g[e,k]
// aug=[agg|x] -> relu(@[Wo1_agg;Wo1_x]+bo1) -> relu(@Wo2+bo2) -> @Wo3+bo3; out=x+pred.
// GEMMs via v_mfma_f32_16x16x32_f16; W2 from LDS-staged transpose (R13).
// CHANGES vs R13: (1) edge loop n-split: af[2][2] packed once, acc[2][2] per half
//   -> peak live regs ~82, fits the unified VGPR/AGPR budget, no spill (was 47MB).
// (2) LDS 48.1->38.9KB (g fp16; aug 32x68, layer-1 K-tail synthesized from x_l)
//   -> 4 blocks/CU, __launch_bounds__(256,4).
// MFMA layout (16x16x32): A: row=l&15, k=8*(l>>4)+e; B: col=l&15, k=8*(l>>4)+e;
//                         D: col=l&15, row=4*(l>>4)+reg.

typedef _Float16     f16x8 __attribute__((ext_vector_type(8)));
typedef float        f32x4 __attribute__((ext_vector_type(4)));
typedef unsigned int u32x4 __attribute__((ext_vector_type(4)));

static __device__ __forceinline__ f16x8 pack8(float a0, float b0, float a1, float b1,
                                              float a2, float b2, float a3, float b3)
{
    u32x4 u;
    u.x = __builtin_bit_cast(unsigned int, __builtin_amdgcn_cvt_pkrtz(a0, b0));
    u.y = __builtin_bit_cast(unsigned int, __builtin_amdgcn_cvt_pkrtz(a1, b1));
    u.z = __builtin_bit_cast(unsigned int, __builtin_amdgcn_cvt_pkrtz(a2, b2));
    u.w = __builtin_bit_cast(unsigned int, __builtin_amdgcn_cvt_pkrtz(a3, b3));
    return __builtin_bit_cast(f16x8, u);
}

__global__ __launch_bounds__(256, 4)
void nri_fused(const float* __restrict__ inputs,
               const float* __restrict__ rgraph,
               const float* __restrict__ W1,  const float* __restrict__ b1,
               const float* __restrict__ W2,  const float* __restrict__ b2,
               const float* __restrict__ Wo1, const float* __restrict__ bo1,
               const float* __restrict__ Wo2, const float* __restrict__ bo2,
               const float* __restrict__ Wo3, const float* __restrict__ bo3,
               float* __restrict__ out)
{
    // floats: x 0(128) | g16 128(1984 halves=992) | S 1120(32x68) | R 3296(32x68) |
    //         aug 5472(32x68) | w2t 7648(64x72 halves=2304) = 9952 fl = 39808 B
    // overlays: h_l (32x136 halves=2176 fl) @7648 (node phase; w2t dead)
    //           p2 (32x132=4224 fl) @1120 over S+R (4352 fl; dead after edge phase)
    __shared__ float smem[9952];
    float* x_l = smem;
    _Float16* g16 = reinterpret_cast<_Float16*>(smem + 128);
    float* S   = smem + 1120;
    float* R   = smem + 3296;
    float* aug = smem + 5472;
    _Float16* w2t = reinterpret_cast<_Float16*>(smem + 7648);
    _Float16* h_l = reinterpret_cast<_Float16*>(smem + 7648);
    float* p2  = smem + 1120;

    const int tid  = threadIdx.x;
    const int b    = blockIdx.x >> 8;
    const int t    = blockIdx.x & 255;
    const int w    = tid >> 6;
    const int lane = tid & 63;
    const int q    = lane & 15;
    const int g4   = lane >> 4;

    // ---- stage x, g (fp16) ----
    if (tid < 32)
        reinterpret_cast<float4*>(x_l)[tid] =
            *reinterpret_cast<const float4*>(inputs + ((size_t)(b * 32 + tid) * 256 + t) * 4);
    for (int idx = tid; idx < 1984; idx += 256) g16[idx] = (_Float16)rgraph[idx];

    float agg_acc[8];
    #pragma unroll
    for (int rr = 0; rr < 8; ++rr) agg_acc[rr] = 0.f;

    for (int k = 0; k < 2; ++k) {
        __syncthreads();   // x_l ready (k=0); S/R/w2t free for restage (k=1)
        // ---- stage S (sender proj + b1), R (receiver proj), stride 68 ----
        for (int idx = tid; idx < 2048; idx += 256) {
            const int j = idx >> 6, kk = idx & 63;
            const float4 xj = reinterpret_cast<const float4*>(x_l)[j];
            const float* wp = W1 + k * 512 + kk;
            float s = b1[k * 64 + kk], r = 0.f;
            s = fmaf(xj.x, wp[0],   s);  r = fmaf(xj.x, wp[256], r);
            s = fmaf(xj.y, wp[64],  s);  r = fmaf(xj.y, wp[320], r);
            s = fmaf(xj.z, wp[128], s);  r = fmaf(xj.z, wp[384], r);
            s = fmaf(xj.w, wp[192], s);  r = fmaf(xj.w, wp[448], r);
            S[j * 68 + kk] = s;
            R[j * 68 + kk] = r;
        }
        // ---- stage W2T[m][kk] fp16, stride 72 ----
        for (int idx = tid; idx < 4096; idx += 256) {
            const int kk = idx >> 6, m = idx & 63;
            w2t[m * 72 + kk] = (_Float16)W2[k * 4096 + idx];
        }
        float bb[4];
        #pragma unroll
        for (int n = 0; n < 4; ++n) bb[n] = b2[k * 64 + 16 * n + q];
        __syncthreads();   // S,R,w2t visible

        // ---- per-receiver edge GEMM, no barriers ----
        #pragma unroll
        for (int rr = 0; rr < 8; ++rr) {
            const int i = w * 8 + rr;
            // pack all A-fragments once (af[m][s], 16 VGPRs)
            f16x8 af[2][2];
            #pragma unroll
            for (int s = 0; s < 2; ++s) {
                const float* rp = R + i * 68 + 32 * s + 8 * g4;
                const float4 Rv0 = *reinterpret_cast<const float4*>(rp);
                const float4 Rv1 = *reinterpret_cast<const float4*>(rp + 4);
                #pragma unroll
                for (int m = 0; m < 2; ++m) {
                    const int r = 16 * m + q;
                    const int j = (r == 31) ? 0 : ((r < i) ? r : r + 1);
                    const float* sp = S + j * 68 + 32 * s + 8 * g4;
                    const float4 s0 = *reinterpret_cast<const float4*>(sp);
                    const float4 s1 = *reinterpret_cast<const float4*>(sp + 4);
                    af[m][s] = pack8(
                        fmaxf(s0.x + Rv0.x, 0.f), fmaxf(s0.y + Rv0.y, 0.f),
                        fmaxf(s0.z + Rv0.z, 0.f), fmaxf(s0.w + Rv0.w, 0.f),
                        fmaxf(s1.x + Rv1.x, 0.f), fmaxf(s1.y + Rv1.y, 0.f),
                        fmaxf(s1.z + Rv1.z, 0.f), fmaxf(s1.w + Rv1.w, 0.f));
                }
            }
            // preload g values for this receiver (8 floats)
            float gvr[8];
            #pragma unroll
            for (int m = 0; m < 2; ++m)
                #pragma unroll
                for (int reg = 0; reg < 4; ++reg) {
                    const int row = 16 * m + 4 * g4 + reg;
                    gvr[m * 4 + reg] =
                        (row < 31) ? (float)g16[(31 * i + row) * 2 + k] : 0.f;
                }
            float part[4];
            // two n-halves: acc[2][2] = 16 regs peak
            #pragma unroll
            for (int nh = 0; nh < 2; ++nh) {
                f32x4 acc[2][2];
                #pragma unroll
                for (int m = 0; m < 2; ++m)
                    #pragma unroll
                    for (int n2 = 0; n2 < 2; ++n2) {
                        const float bv = bb[2 * nh + n2];
                        acc[m][n2][0] = bv; acc[m][n2][1] = bv;
                        acc[m][n2][2] = bv; acc[m][n2][3] = bv;
                    }
                #pragma unroll
                for (int s = 0; s < 2; ++s)
                    #pragma unroll
                    for (int n2 = 0; n2 < 2; ++n2) {
                        const f16x8 wb = *reinterpret_cast<const f16x8*>(
                            w2t + (16 * (2 * nh + n2) + q) * 72 + 32 * s + 8 * g4);
                        acc[0][n2] = __builtin_amdgcn_mfma_f32_16x16x32_f16(
                            af[0][s], wb, acc[0][n2], 0, 0, 0);
                        acc[1][n2] = __builtin_amdgcn_mfma_f32_16x16x32_f16(
                            af[1][s], wb, acc[1][n2], 0, 0, 0);
                    }
                float p0 = 0.f, p1 = 0.f;
                #pragma unroll
                for (int m = 0; m < 2; ++m)
                    #pragma unroll
                    for (int reg = 0; reg < 4; ++reg) {
                        const float gv = gvr[m * 4 + reg];
                        p0 = fmaf(fmaxf(acc[m][0][reg], 0.f), gv, p0);
                        p1 = fmaf(fmaxf(acc[m][1][reg], 0.f), gv, p1);
                    }
                part[2 * nh + 0] = p0;
                part[2 * nh + 1] = p1;
            }
            #pragma unroll
            for (int n = 0; n < 4; ++n) {
                part[n] += __shfl_xor(part[n], 16);
                part[n] += __shfl_xor(part[n], 32);
            }
            const float v = (g4 == 0) ? part[0] : (g4 == 1) ? part[1]
                          : (g4 == 2) ? part[2] : part[3];
            agg_acc[rr] += v;
        }
    }

    // ---- agg -> aug (32x68) ----
    #pragma unroll
    for (int rr = 0; rr < 8; ++rr)
        aug[(w * 8 + rr) * 68 + 16 * g4 + q] = agg_acc[rr];
    __syncthreads();

    const int c0 = 32 * w;   // wave's 32-col slice of NH=128

    // ---- node layer 1: [agg(64)|x(4)|0] @ Wo1' -> h (fp16, stride 136) ----
    {
        f16x8 bf[2][3];
        #pragma unroll
        for (int n = 0; n < 2; ++n)
            #pragma unroll
            for (int s = 0; s < 3; ++s) {
                const int col = c0 + 16 * n + q;
                const int ka = 32 * s + 8 * g4;
                float vv[8];
                #pragma unroll
                for (int e2 = 0; e2 < 8; ++e2) {
                    const int kx = ka + e2;
                    vv[e2] = (kx < 64) ? Wo1[(4 + kx) * 128 + col]
                           : ((kx < 68) ? Wo1[(kx - 64) * 128 + col] : 0.f);
                }
                bf[n][s] = pack8(vv[0], vv[1], vv[2], vv[3], vv[4], vv[5], vv[6], vv[7]);
            }
        f32x4 acc[2][2];
        #pragma unroll
        for (int m = 0; m < 2; ++m)
            #pragma unroll
            for (int n = 0; n < 2; ++n) {
                const float bv = bo1[c0 + 16 * n + q];
                acc[m][n][0] = bv; acc[m][n][1] = bv; acc[m][n][2] = bv; acc[m][n][3] = bv;
            }
        #pragma unroll
        for (int s = 0; s < 2; ++s) {     // agg K-blocks from aug
            f16x8 afr[2];
            #pragma unroll
            for (int m = 0; m < 2; ++m) {
                const float* ap = aug + (16 * m + q) * 68 + 32 * s + 8 * g4;
                const float4 a0 = *reinterpret_cast<const float4*>(ap);
                const float4 a1 = *reinterpret_cast<const float4*>(ap + 4);
                afr[m] = pack8(a0.x, a0.y, a0.z, a0.w, a1.x, a1.y, a1.z, a1.w);
            }
            #pragma unroll
            for (int m = 0; m < 2; ++m)
                #pragma unroll
                for (int n = 0; n < 2; ++n)
                    acc[m][n] = __builtin_amdgcn_mfma_f32_16x16x32_f16(
                        afr[m], bf[n][s], acc[m][n], 0, 0, 0);
        }
        {                                  // K-tail: [x(4)|0(28)] synthesized
            const f16x8 zero8 = __builtin_bit_cast(f16x8, (u32x4){0u, 0u, 0u, 0u});
            f16x8 afr[2];
            #pragma unroll
            for (int m = 0; m < 2; ++m) {
                const float4 xr = *reinterpret_cast<const float4*>(x_l + (16 * m + q) * 4);
                afr[m] = (g4 == 0)
                    ? pack8(xr.x, xr.y, xr.z, xr.w, 0.f, 0.f, 0.f, 0.f)
                    : zero8;
            }
            #pragma unroll
            for (int m = 0; m < 2; ++m)
                #pragma unroll
                for (int n = 0; n < 2; ++n)
                    acc[m][n] = __builtin_amdgcn_mfma_f32_16x16x32_f16(
                        afr[m], bf[n][2], acc[m][n], 0, 0, 0);
        }
        #pragma unroll
        for (int m = 0; m < 2; ++m)
            #pragma unroll
            for (int n = 0; n < 2; ++n)
                #pragma unroll
                for (int reg = 0; reg < 4; ++reg) {
                    const int row = 16 * m + 4 * g4 + reg;
                    h_l[row * 136 + c0 + 16 * n + q] = (_Float16)fmaxf(acc[m][n][reg], 0.f);
                }
    }
    __syncthreads();

    // ---- node layer 2: h(32x128 fp16) @ Wo2 -> p2 (fp32, stride 132) ----
    {
        f16x8 bf[2][4];
        #pragma unroll
        for (int n = 0; n < 2; ++n)
            #pragma unroll
            for (int s = 0; s < 4; ++s) {
                const int col = c0 + 16 * n + q;
                const int ka = 32 * s + 8 * g4;
                bf[n][s] = pack8(Wo2[(ka + 0) * 128 + col], Wo2[(ka + 1) * 128 + col],
                                 Wo2[(ka + 2) * 128 + col], Wo2[(ka + 3) * 128 + col],
                                 Wo2[(ka + 4) * 128 + col], Wo2[(ka + 5) * 128 + col],
                                 Wo2[(ka + 6) * 128 + col], Wo2[(ka + 7) * 128 + col]);
            }
        f32x4 acc[2][2];
        #pragma unroll
        for (int m = 0; m < 2; ++m)
            #pragma unroll
            for (int n = 0; n < 2; ++n) {
                const float bv = bo2[c0 + 16 * n + q];
                acc[m][n][0] = bv; acc[m][n][1] = bv; acc[m][n][2] = bv; acc[m][n][3] = bv;
            }
        #pragma unroll
        for (int s = 0; s < 4; ++s) {
            f16x8 afr[2];
            #pragma unroll
            for (int m = 0; m < 2; ++m)
                afr[m] = *reinterpret_cast<const f16x8*>(
                    h_l + (16 * m + q) * 136 + 32 * s + 8 * g4);
            #pragma unroll
            for (int m = 0; m < 2; ++m)
                #pragma unroll
                for (int n = 0; n < 2; ++n)
                    acc[m][n] = __builtin_amdgcn_mfma_f32_16x16x32_f16(
                        afr[m], bf[n][s], acc[m][n], 0, 0, 0);
        }
        #pragma unroll
        for (int m = 0; m < 2; ++m)
            #pragma unroll
            for (int n = 0; n < 2; ++n)
                #pragma unroll
                for (int reg = 0; reg < 4; ++reg) {
                    const int row = 16 * m + 4 * g4 + reg;
                    p2[row * 132 + c0 + 16 * n + q] = fmaxf(acc[m][n][reg], 0.f);
                }
    }
    __syncthreads();

    // ---- layer 3 (fp32 VALU) + residual + store (skip t == 255) ----
    if (tid < 128 && t < 255) {
        const int rr3 = tid >> 2;
        const int dd  = tid & 3;
        float a0 = 0.f, a1 = 0.f, a2 = 0.f, a3 = 0.f;
        const float* pr = p2 + rr3 * 132;
        for (int d = 0; d < 128; d += 4) {
            a0 = fmaf(pr[d + 0], Wo3[(d + 0) * 4 + dd], a0);
            a1 = fmaf(pr[d + 1], Wo3[(d + 1) * 4 + dd], a1);
            a2 = fmaf(pr[d + 2], Wo3[(d + 2) * 4 + dd], a2);
            a3 = fmaf(pr[d + 3], Wo3[(d + 3) * 4 + dd], a3);
        }
        const float pred = ((a0 + a1) + (a2 + a3)) + bo3[dd];
        out[((size_t)(b * 32 + rr3) * 255 + t) * 4 + dd] = x_l[rr3 * 4 + dd] + pred;
    }
}

__global__ void copy_relgraph(const float* __restrict__ g, float* __restrict__ out2)
{
    const int idx = blockIdx.x * 256 + threadIdx.x;
    if (idx < 15872) out2[idx] = g[idx % 1984];
}

extern "C" void kernel_launch(void* const* d_in, const int* in_sizes, int n_in,
                              void* d_out, int out_size, void* d_ws, size_t ws_size,
                              hipStream_t stream)
{
    (void)in_sizes; (void)n_in; (void)d_ws; (void)ws_size; (void)out_size;
    const float* inputs    = (const float*)d_in[0];
    const float* rel_graph = (const float*)d_in[3];
    const float* W1  = (const float*)d_in[4];
    const float* b1  = (const float*)d_in[5];
    const float* W2  = (const float*)d_in[6];
    const float* b2  = (const float*)d_in[7];
    const float* Wo1 = (const float*)d_in[8];
    const float* bo1 = (const float*)d_in[9];
    const float* Wo2 = (const float*)d_in[10];
    const float* bo2 = (const float*)d_in[11];
    const float* Wo3 = (const float*)d_in[12];
    const float* bo3 = (const float*)d_in[13];
    float* out = (float*)d_out;

    nri_fused<<<2048, 256, 0, stream>>>(inputs, rel_graph, W1, b1, W2, b2,
                                        Wo1, bo1, Wo2, bo2, Wo3, bo3, out);
    copy_relgraph<<<62, 256, 0, stream>>>(rel_graph, out + 261120);
}